// Round 1
// 895.892 us; speedup vs baseline: 1.8511x; 1.8511x over previous
//
#include <hip/hip_runtime.h>
#include <math.h>

// Fused Swin block on MI355X: B=32, H=W=128, C=128, WS=2, SS=1, NH=8, HD=16
// Single kernel per 16 windows (64 tokens): LN1 -> qkv GEMM -> window attn
// -> proj (chunked per head-group) -> y=x+proj (global, L2-hot) -> LN2 ->
// MLP GEMM1(swapped)+GELU -> chunked hid dbuf -> GEMM2 -> out = y + mlp.
// All GEMMs: v_mfma_f32_16x16x32_bf16, 4-rowfrag register tiling so each
// 16B global weight load feeds 4 MFMAs (was 1:1). Weights pre-transposed
// bf16 in d_ws. MFMA layouts (m89/m91): A[m=lane&15][k=quad*8+j],
// B[k=quad*8+j][n=lane&15] (Wt row n), D col=lane&15 row=quad*4+reg.

typedef __attribute__((ext_vector_type(8))) short short8;
typedef __attribute__((ext_vector_type(8))) unsigned short ushort8;
typedef __attribute__((ext_vector_type(4))) unsigned short ushort4v;
typedef __attribute__((ext_vector_type(4))) float f32x4;

#define MFMA __builtin_amdgcn_mfma_f32_16x16x32_bf16

__device__ inline unsigned short f2bf(float f) {
  union { float f; unsigned u; } v; v.f = f;
  unsigned r = (v.u + 0x7fffu + ((v.u >> 16) & 1u)) >> 16;
  return (unsigned short)r;
}
__device__ inline float bf2f(unsigned short s) {
  union { unsigned u; float f; } v; v.u = ((unsigned)s) << 16;
  return v.f;
}
__device__ inline void ld16(const unsigned short* p, float* o) {
  ushort8 a = *(const ushort8*)p;
  ushort8 b = *(const ushort8*)(p + 8);
  #pragma unroll
  for (int t = 0; t < 8; ++t) { o[t] = bf2f(a[t]); o[8 + t] = bf2f(b[t]); }
}

namespace {

// ws layout (bf16 elements): qkv_wt[384][128] @0, proj_wt[128][128] @49152,
// w1t[256][128] @65536, w2t[128][256] @98304. Total 131072 el = 256KB.
__global__ __launch_bounds__(256) void prep_weights(
    const float* __restrict__ qkv_w, const float* __restrict__ proj_w,
    const float* __restrict__ w1, const float* __restrict__ w2,
    unsigned short* __restrict__ ws)
{
  const int idx = blockIdx.x * 256 + threadIdx.x;  // grid covers 131072
  float v;
  if (idx < 49152) {            // qkv_wt[n][k] = qkv_w[k][n], n<384,k<128
    const int n = idx >> 7, k = idx & 127; v = qkv_w[k * 384 + n];
  } else if (idx < 65536) {     // proj_wt
    const int l = idx - 49152; const int n = l >> 7, k = l & 127;
    v = proj_w[k * 128 + n];
  } else if (idx < 98304) {     // w1t[n][k], n<256,k<128
    const int l = idx - 65536; const int n = l >> 7, k = l & 127;
    v = w1[k * 256 + n];
  } else {                      // w2t[n][k], n<128,k<256
    const int l = idx - 98304; const int n = l >> 8, k = l & 255;
    v = w2[k * 128 + n];
  }
  ws[idx] = f2bf(v);
}

__global__ __launch_bounds__(256, 3) void swin_fused(
    const float* __restrict__ x,
    const unsigned short* __restrict__ wsw,
    const float* __restrict__ qkv_b,
    const float* __restrict__ proj_b,
    const float* __restrict__ rpb,
    const float* __restrict__ g1,
    const float* __restrict__ b1,
    const float* __restrict__ g2,
    const float* __restrict__ bt2,
    const float* __restrict__ bias1,
    const float* __restrict__ bias2,
    float* __restrict__ out)
{
  // LDS union: 256B gsrc | 17408B Asm(=ys) | 25600B qkvh(=hid0/hid1) | 9216B ohsc
  __shared__ __align__(16) unsigned char smem[52480];
  int* gsrc = (int*)smem;
  unsigned short (*Asm)[136]  = (unsigned short(*)[136])(smem + 256);
  unsigned short (*qkvh)[200] = (unsigned short(*)[200])(smem + 17664);
  unsigned short (*ohsc)[72]  = (unsigned short(*)[72])(smem + 43264);
  unsigned short (*ys)[136]   = (unsigned short(*)[136])(smem + 256);    // alias Asm
  unsigned short (*hid0)[72]  = (unsigned short(*)[72])(smem + 17664);   // alias qkvh
  unsigned short (*hid1)[72]  = (unsigned short(*)[72])(smem + 26880);   // alias qkvh

  const int tid = threadIdx.x;
  const int n0 = blockIdx.x * 16;

  // ---- gather + LN1 -> bf16 Asm ----
  {
    const int r = tid >> 2;
    const int part = tid & 3;
    const int n = n0 + (r >> 2);
    const int s = r & 3;
    const int b = n >> 12;
    const int rem = n & 4095;
    const int wh = rem >> 6, wwi = rem & 63;
    const int hp = (2 * wh + (s >> 1) + 1) & 127;
    const int wp = (2 * wwi + (s & 1) + 1) & 127;
    const int src = (b << 14) + (hp << 7) + wp;
    if (part == 0) gsrc[r] = src;
    const float4* xr = (const float4*)(x + (size_t)src * 128 + part * 32);
    float4 v[8];
    float sum = 0.f, ssq = 0.f;
    #pragma unroll
    for (int i = 0; i < 8; ++i) {
      v[i] = xr[i];
      sum += v[i].x + v[i].y + v[i].z + v[i].w;
      ssq += v[i].x * v[i].x + v[i].y * v[i].y + v[i].z * v[i].z + v[i].w * v[i].w;
    }
    sum += __shfl_xor(sum, 1, 4); sum += __shfl_xor(sum, 2, 4);
    ssq += __shfl_xor(ssq, 1, 4); ssq += __shfl_xor(ssq, 2, 4);
    const float mean = sum * 0.0078125f;
    const float var = ssq * 0.0078125f - mean * mean;
    const float rstd = rsqrtf(var + 1e-5f);
    const int c0 = part * 32;
    #pragma unroll
    for (int i = 0; i < 8; ++i) {
      const int c = c0 + i * 4;
      const float4 gv = *(const float4*)(g1 + c);
      const float4 bv = *(const float4*)(b1 + c);
      ushort4v h4;
      h4.x = f2bf((v[i].x - mean) * rstd * gv.x + bv.x);
      h4.y = f2bf((v[i].y - mean) * rstd * gv.y + bv.y);
      h4.z = f2bf((v[i].z - mean) * rstd * gv.z + bv.z);
      h4.w = f2bf((v[i].w - mean) * rstd * gv.w + bv.w);
      *(ushort4v*)&Asm[r][c] = h4;
    }
  }
  __syncthreads();

  const int lane = tid & 63;
  const int wave = tid >> 6;
  const int l15 = lane & 15;
  const int quad = lane >> 4;

  const unsigned short* qkv_wt = wsw;            // [384][128]
  const unsigned short* proj_wt = wsw + 49152;   // [128][128]

  f32x4 accp[4][2] = {};   // proj accumulator, persists across head-groups

  for (int g = 0; g < 2; ++g) {
    // ---- qkv GEMM: wave w = local head w of group g; 3 col-tiles (q,k,v),
    //      4 row-frags -> each 16B weight load feeds 4 MFMAs ----
    {
      f32x4 acc[4][3] = {};
      const int nq = g * 64 + wave * 16 + l15;
      const unsigned short* bq = qkv_wt + (size_t)nq * 128;
      const unsigned short* bk = qkv_wt + (size_t)(128 + nq) * 128;
      const unsigned short* bv = qkv_wt + (size_t)(256 + nq) * 128;
      #pragma unroll
      for (int ks = 0; ks < 4; ++ks) {
        const int k0 = ks * 32 + quad * 8;
        const short8 fq = *(const short8*)(bq + k0);
        const short8 fk = *(const short8*)(bk + k0);
        const short8 fv = *(const short8*)(bv + k0);
        #pragma unroll
        for (int rf = 0; rf < 4; ++rf) {
          const short8 af = *(const short8*)&Asm[rf * 16 + l15][k0];
          acc[rf][0] = MFMA(af, fq, acc[rf][0], 0, 0, 0);
          acc[rf][1] = MFMA(af, fk, acc[rf][1], 0, 0, 0);
          acc[rf][2] = MFMA(af, fv, acc[rf][2], 0, 0, 0);
        }
      }
      const float bbq = qkv_b[nq];
      const float bbk = qkv_b[128 + nq];
      const float bbv = qkv_b[256 + nq];
      #pragma unroll
      for (int rf = 0; rf < 4; ++rf) {
        #pragma unroll
        for (int r = 0; r < 4; ++r) {
          const int row = rf * 16 + quad * 4 + r;
          qkvh[row][wave * 16 + l15]       = f2bf((acc[rf][0][r] + bbq) * 0.25f);
          qkvh[row][64 + wave * 16 + l15]  = f2bf(acc[rf][1][r] + bbk);
          qkvh[row][128 + wave * 16 + l15] = f2bf(acc[rf][2][r] + bbv);
        }
      }
    }
    __syncthreads();

    // ---- attention: thread = (window, local head, query token) ----
    {
      const int w = tid >> 4;
      const int hl = (tid >> 2) & 3;
      const int i = tid & 3;
      const int h = g * 4 + hl;
      const int row_i = 4 * w + i;
      const int n = n0 + w;
      const int rem = n & 4095;
      const int wh = rem >> 6, wwi = rem & 63;
      const int yi = 2 * wh + (i >> 1);
      const int xi = 2 * wwi + (i & 1);
      const int regi = ((yi < 126) ? 0 : ((yi == 126) ? 1 : 2)) * 3
                     + ((xi < 126) ? 0 : ((xi == 126) ? 1 : 2));
      float q[16];
      ld16(&qkvh[row_i][hl * 16], q);
      float p[4];
      #pragma unroll
      for (int j = 0; j < 4; ++j) {
        float kk[16];
        ld16(&qkvh[4 * w + j][64 + hl * 16], kk);
        float d = 0.f;
        #pragma unroll
        for (int dd = 0; dd < 16; ++dd) d += q[dd] * kk[dd];
        const int idx = ((i >> 1) - (j >> 1) + 1) * 3 + ((i & 1) - (j & 1) + 1);
        d += rpb[idx * 8 + h];
        const int yj = 2 * wh + (j >> 1);
        const int xj = 2 * wwi + (j & 1);
        const int regj = ((yj < 126) ? 0 : ((yj == 126) ? 1 : 2)) * 3
                       + ((xj < 126) ? 0 : ((xj == 126) ? 1 : 2));
        if (regi != regj) d -= 100.f;
        p[j] = d;
      }
      const float mx = fmaxf(fmaxf(p[0], p[1]), fmaxf(p[2], p[3]));
      float es = 0.f;
      #pragma unroll
      for (int j = 0; j < 4; ++j) { p[j] = expf(p[j] - mx); es += p[j]; }
      const float inv = 1.f / es;
      float o[16];
      #pragma unroll
      for (int dd = 0; dd < 16; ++dd) o[dd] = 0.f;
      #pragma unroll
      for (int j = 0; j < 4; ++j) {
        float vv[16];
        ld16(&qkvh[4 * w + j][128 + hl * 16], vv);
        #pragma unroll
        for (int dd = 0; dd < 16; ++dd) o[dd] += p[j] * vv[dd];
      }
      ushort8 oa, ob;
      #pragma unroll
      for (int dd = 0; dd < 8; ++dd) {
        oa[dd] = f2bf(o[dd] * inv);
        ob[dd] = f2bf(o[8 + dd] * inv);
      }
      *(ushort8*)&ohsc[row_i][hl * 16] = oa;
      *(ushort8*)&ohsc[row_i][hl * 16 + 8] = ob;
    }
    __syncthreads();

    // ---- proj partial: K-chunk g*64..g*64+63 consumed immediately ----
    {
      #pragma unroll
      for (int ks = 0; ks < 2; ++ks) {
        const int k0 = ks * 32 + quad * 8;
        const short8 f0 = *(const short8*)(proj_wt + (size_t)(wave * 32 + l15) * 128 + g * 64 + k0);
        const short8 f1 = *(const short8*)(proj_wt + (size_t)(wave * 32 + 16 + l15) * 128 + g * 64 + k0);
        #pragma unroll
        for (int rf = 0; rf < 4; ++rf) {
          const short8 af = *(const short8*)&ohsc[rf * 16 + l15][k0];
          accp[rf][0] = MFMA(af, f0, accp[rf][0], 0, 0, 0);
          accp[rf][1] = MFMA(af, f1, accp[rf][1], 0, 0, 0);
        }
      }
    }
  }

  // ---- y = x + proj + bias -> global (L2-hot scratch; skip2 for MLP) ----
  #pragma unroll
  for (int rf = 0; rf < 4; ++rf) {
    #pragma unroll
    for (int r = 0; r < 4; ++r) {
      const int row = rf * 16 + quad * 4 + r;
      const int src = gsrc[row];
      float* orow = out + (size_t)src * 128;
      const float* xr = x + (size_t)src * 128;
      #pragma unroll
      for (int nt = 0; nt < 2; ++nt) {
        const int col = wave * 32 + nt * 16 + l15;
        orow[col] = accp[rf][nt][r] + proj_b[col] + xr[col];
      }
    }
  }
  __syncthreads();

  // ---- LN2 (reads y back from global, rows of this block only) -> ys ----
  {
    const int r = tid >> 2;
    const int part = tid & 3;
    const int src = gsrc[r];
    const float4* yr = (const float4*)(out + (size_t)src * 128 + part * 32);
    float4 v[8];
    float sum = 0.f, ssq = 0.f;
    #pragma unroll
    for (int i = 0; i < 8; ++i) {
      v[i] = yr[i];
      sum += v[i].x + v[i].y + v[i].z + v[i].w;
      ssq += v[i].x * v[i].x + v[i].y * v[i].y + v[i].z * v[i].z + v[i].w * v[i].w;
    }
    sum += __shfl_xor(sum, 1, 4); sum += __shfl_xor(sum, 2, 4);
    ssq += __shfl_xor(ssq, 1, 4); ssq += __shfl_xor(ssq, 2, 4);
    const float mean = sum * 0.0078125f;
    const float var = ssq * 0.0078125f - mean * mean;
    const float rstd = rsqrtf(var + 1e-5f);
    const int c0 = part * 32;
    #pragma unroll
    for (int i = 0; i < 8; ++i) {
      const int c = c0 + i * 4;
      const float4 gv = *(const float4*)(g2 + c);
      const float4 bv = *(const float4*)(bt2 + c);
      ushort4v h4;
      h4.x = f2bf((v[i].x - mean) * rstd * gv.x + bv.x);
      h4.y = f2bf((v[i].y - mean) * rstd * gv.y + bv.y);
      h4.z = f2bf((v[i].z - mean) * rstd * gv.z + bv.z);
      h4.w = f2bf((v[i].w - mean) * rstd * gv.w + bv.w);
      *(ushort4v*)&ys[r][c] = h4;
    }
  }
  __syncthreads();

  // ---- MLP: GEMM1 swapped-form (D[h][m]) per 64-h chunk + GELU -> hid dbuf,
  //      GEMM2 accumulates per chunk; G1(c+1) issued before G2(c) ----
  const unsigned short* w1t = wsw + 65536;   // [256][128]
  const unsigned short* w2t = wsw + 98304;   // [128][256]
  f32x4 am[4][2] = {};

  auto G1 = [&](int c, unsigned short (*hb)[72]) {
    f32x4 hacc[4] = {};
    const int ht = c * 4 + wave;
    const unsigned short* arow = w1t + (size_t)(ht * 16 + l15) * 128;
    #pragma unroll
    for (int ks = 0; ks < 4; ++ks) {
      const int k0 = ks * 32 + quad * 8;
      const short8 af = *(const short8*)(arow + k0);           // w1t as A-frag
      #pragma unroll
      for (int mt = 0; mt < 4; ++mt) {
        const short8 bf = *(const short8*)&ys[mt * 16 + l15][k0];  // ys as B-frag
        hacc[mt] = MFMA(af, bf, hacc[mt], 0, 0, 0);
      }
    }
    const int hbase = ht * 16 + quad * 4;
    const float4 bb = *(const float4*)(bias1 + hbase);
    #pragma unroll
    for (int mt = 0; mt < 4; ++mt) {
      ushort4v pk;
      #pragma unroll
      for (int r = 0; r < 4; ++r) {
        float v = hacc[mt][r] + ((const float*)&bb)[r];
        v = 0.5f * v * (1.f + erff(v * 0.70710678118654752f));
        pk[r] = f2bf(v);
      }
      // hid[m][h_local]: token row from l15, 4 contiguous h per b64 write
      *(ushort4v*)&hb[mt * 16 + l15][wave * 16 + quad * 4] = pk;
    }
  };
  auto G2 = [&](int c, const unsigned short (*hb)[72]) {
    #pragma unroll
    for (int ks = 0; ks < 2; ++ks) {
      const int k0 = ks * 32 + quad * 8;
      const int kg = c * 64 + k0;
      const short8 f0 = *(const short8*)(w2t + (size_t)(wave * 32 + l15) * 256 + kg);
      const short8 f1 = *(const short8*)(w2t + (size_t)(wave * 32 + 16 + l15) * 256 + kg);
      #pragma unroll
      for (int rf = 0; rf < 4; ++rf) {
        const short8 af = *(const short8*)&hb[rf * 16 + l15][k0];
        am[rf][0] = MFMA(af, f0, am[rf][0], 0, 0, 0);
        am[rf][1] = MFMA(af, f1, am[rf][1], 0, 0, 0);
      }
    }
  };

  G1(0, hid0);
  __syncthreads();
  G1(1, hid1); G2(0, hid0);
  __syncthreads();
  G1(2, hid0); G2(1, hid1);
  __syncthreads();
  G1(3, hid1); G2(2, hid0);
  __syncthreads();
  G2(3, hid1);

  // ---- final: out = y + bias2 + mlp ----
  #pragma unroll
  for (int rf = 0; rf < 4; ++rf) {
    #pragma unroll
    for (int r = 0; r < 4; ++r) {
      const int row = rf * 16 + quad * 4 + r;
      const int src = gsrc[row];
      float* orow = out + (size_t)src * 128;
      #pragma unroll
      for (int nt = 0; nt < 2; ++nt) {
        const int col = wave * 32 + nt * 16 + l15;
        orow[col] += bias2[col] + am[rf][nt][r];
      }
    }
  }
}

} // namespace

extern "C" void kernel_launch(void* const* d_in, const int* in_sizes, int n_in,
                              void* d_out, int out_size, void* d_ws, size_t ws_size,
                              hipStream_t stream) {
  const float* x      = (const float*)d_in[0];
  const float* qkv_w  = (const float*)d_in[1];
  const float* qkv_b  = (const float*)d_in[2];
  const float* proj_w = (const float*)d_in[3];
  const float* proj_b = (const float*)d_in[4];
  const float* rpb    = (const float*)d_in[5];
  const float* g1     = (const float*)d_in[6];
  const float* b1     = (const float*)d_in[7];
  const float* g2     = (const float*)d_in[8];
  const float* b2     = (const float*)d_in[9];
  const float* w1     = (const float*)d_in[10];
  const float* bias1  = (const float*)d_in[11];
  const float* w2     = (const float*)d_in[12];
  const float* bias2  = (const float*)d_in[13];
  float* out = (float*)d_out;
  unsigned short* wsw = (unsigned short*)d_ws;

  hipLaunchKernelGGL(prep_weights, dim3(512), dim3(256), 0, stream,
                     qkv_w, proj_w, w1, w2, wsw);
  hipLaunchKernelGGL(swin_fused, dim3(8192), dim3(256), 0, stream,
                     x, wsw, qkv_b, proj_b, rpb, g1, b1, g2, b2, bias1, bias2, out);
}

// Round 2
// 892.051 us; speedup vs baseline: 1.8590x; 1.0043x over previous
//
#include <hip/hip_runtime.h>
#include <math.h>

// Fused Swin block on MI355X: B=32, H=W=128, C=128, WS=2, SS=1, NH=8, HD=16
// One block = 16 windows (64 tokens). LN1 -> qkv GEMM (reg acc, per-head waves)
// -> MFMA attention (zero-padded K=32; softmax lane-local; P via 2 bpermutes,
// V via 4 bpermutes; tiny per-wave Q/K LDS transpose stage) -> proj GEMM K=128
// -> y kept in REGISTERS (LN2 stats via shfl + 2KB LDS partials; no y global
// roundtrip, out written exactly once) -> MLP chunked dbuf GEMMs.
// LDS 40,192 B -> 4 blocks/CU (16 waves). Weight frags prefetched one phase
// ahead (manual hoist across barriers). 8 barriers (was 11).
// MFMA layouts (m89/m91): A[m=lane&15][k=quad*8+j], B[k=quad*8+j][n=lane&15],
// D col=lane&15 row=quad*4+reg.

typedef __attribute__((ext_vector_type(8))) short short8;
typedef __attribute__((ext_vector_type(8))) unsigned short ushort8;
typedef __attribute__((ext_vector_type(4))) unsigned short ushort4v;
typedef __attribute__((ext_vector_type(4))) float f32x4;

#define MFMA __builtin_amdgcn_mfma_f32_16x16x32_bf16

__device__ inline unsigned short f2bf(float f) {
  union { float f; unsigned u; } v; v.f = f;
  unsigned r = (v.u + 0x7fffu + ((v.u >> 16) & 1u)) >> 16;
  return (unsigned short)r;
}
__device__ inline unsigned pk2(float a, float b) {
  return (unsigned)f2bf(a) | ((unsigned)f2bf(b) << 16);
}
union V4 { unsigned u[4]; short8 s; };

namespace {

// ws layout (bf16 elements): qkv_wt[384][128] @0, proj_wt[128][128] @49152,
// w1t[256][128] @65536, w2t[128][256] @98304. Total 131072 el = 256KB.
__global__ __launch_bounds__(256) void prep_weights(
    const float* __restrict__ qkv_w, const float* __restrict__ proj_w,
    const float* __restrict__ w1, const float* __restrict__ w2,
    unsigned short* __restrict__ ws)
{
  const int idx = blockIdx.x * 256 + threadIdx.x;  // grid covers 131072
  float v;
  if (idx < 49152) {            // qkv_wt[n][k] = qkv_w[k][n], n<384,k<128
    const int n = idx >> 7, k = idx & 127; v = qkv_w[k * 384 + n];
  } else if (idx < 65536) {     // proj_wt
    const int l = idx - 49152; const int n = l >> 7, k = l & 127;
    v = proj_w[k * 128 + n];
  } else if (idx < 98304) {     // w1t[n][k], n<256,k<128
    const int l = idx - 65536; const int n = l >> 7, k = l & 127;
    v = w1[k * 256 + n];
  } else {                      // w2t[n][k], n<128,k<256
    const int l = idx - 98304; const int n = l >> 8, k = l & 255;
    v = w2[k * 128 + n];
  }
  ws[idx] = f2bf(v);
}

__global__ __launch_bounds__(256, 4) void swin_fused(
    const float* __restrict__ x,
    const unsigned short* __restrict__ wsw,
    const float* __restrict__ qkv_b,
    const float* __restrict__ proj_b,
    const float* __restrict__ rpb,
    const float* __restrict__ g1,
    const float* __restrict__ b1,
    const float* __restrict__ g2,
    const float* __restrict__ bt2,
    const float* __restrict__ bias1,
    const float* __restrict__ bias2,
    float* __restrict__ out)
{
  // Regions: [0,256) gsrc | [256,17664) Asm(=ys) | [17664,22784) per-wave QK
  // stage (later: LN2 partials, hid0) | [22784,40192) ohs (later: hid1 tail)
  __shared__ __align__(16) unsigned char smem[40192];
  int* gsrc = (int*)smem;
  unsigned short (*Asm)[136] = (unsigned short(*)[136])(smem + 256);
  unsigned short (*ys)[136]  = (unsigned short(*)[136])(smem + 256);    // alias
  unsigned short (*ohs)[136] = (unsigned short(*)[136])(smem + 22784);
  unsigned short (*hid0)[72] = (unsigned short(*)[72])(smem + 17664);   // alias
  unsigned short (*hid1)[72] = (unsigned short(*)[72])(smem + 26880);   // alias
  float* part = (float*)(smem + 17664);                                 // [64][8]

  const int tid = threadIdx.x;
  const int n0 = blockIdx.x * 16;
  const int lane = tid & 63;
  const int wave = tid >> 6;
  const int l15 = lane & 15;
  const int quad = lane >> 4;
  const f32x4 fz = {0.f, 0.f, 0.f, 0.f};

  const unsigned short* qkv_wt = wsw;            // [384][128]
  const unsigned short* proj_wt = wsw + 49152;   // [128][128]

  // per-wave Q/K transpose stage: [16][20] bf16 each
  unsigned short (*sq)[20] = (unsigned short(*)[20])(smem + 17664 + wave * 1280);
  unsigned short (*sk)[20] = (unsigned short(*)[20])(smem + 17664 + wave * 1280 + 640);

  // ---- prefetch qkv g=0 weight frags (before LN1 barrier) ----
  short8 w0q[4], w0k[4], w0v[4];
  {
    const int nq = wave * 16 + l15;
    const unsigned short* bq = qkv_wt + (size_t)nq * 128;
    const unsigned short* bk = qkv_wt + (size_t)(128 + nq) * 128;
    const unsigned short* bv = qkv_wt + (size_t)(256 + nq) * 128;
    #pragma unroll
    for (int ks = 0; ks < 4; ++ks) {
      const int k0 = ks * 32 + quad * 8;
      w0q[ks] = *(const short8*)(bq + k0);
      w0k[ks] = *(const short8*)(bk + k0);
      w0v[ks] = *(const short8*)(bv + k0);
    }
  }

  // ---- gather + LN1 -> bf16 Asm ----
  {
    const int r = tid >> 2;
    const int partc = tid & 3;
    const int n = n0 + (r >> 2);
    const int s = r & 3;
    const int b = n >> 12;
    const int rem = n & 4095;
    const int wh = rem >> 6, wwi = rem & 63;
    const int hp = (2 * wh + (s >> 1) + 1) & 127;
    const int wp = (2 * wwi + (s & 1) + 1) & 127;
    const int src = (b << 14) + (hp << 7) + wp;
    if (partc == 0) gsrc[r] = src;
    const float4* xr = (const float4*)(x + (size_t)src * 128 + partc * 32);
    float4 v[8];
    float sum = 0.f, ssq = 0.f;
    #pragma unroll
    for (int i = 0; i < 8; ++i) {
      v[i] = xr[i];
      sum += v[i].x + v[i].y + v[i].z + v[i].w;
      ssq += v[i].x * v[i].x + v[i].y * v[i].y + v[i].z * v[i].z + v[i].w * v[i].w;
    }
    sum += __shfl_xor(sum, 1, 4); sum += __shfl_xor(sum, 2, 4);
    ssq += __shfl_xor(ssq, 1, 4); ssq += __shfl_xor(ssq, 2, 4);
    const float mean = sum * 0.0078125f;
    const float var = ssq * 0.0078125f - mean * mean;
    const float rstd = rsqrtf(var + 1e-5f);
    const int c0 = partc * 32;
    #pragma unroll
    for (int i = 0; i < 8; ++i) {
      const int c = c0 + i * 4;
      const float4 gv = *(const float4*)(g1 + c);
      const float4 bv = *(const float4*)(b1 + c);
      ushort4v h4;
      h4.x = f2bf((v[i].x - mean) * rstd * gv.x + bv.x);
      h4.y = f2bf((v[i].y - mean) * rstd * gv.y + bv.y);
      h4.z = f2bf((v[i].z - mean) * rstd * gv.z + bv.z);
      h4.w = f2bf((v[i].w - mean) * rstd * gv.w + bv.w);
      *(ushort4v*)&Asm[r][c] = h4;
    }
  }
  __syncthreads();  // S1

  auto QKV = [&](const short8* wq, const short8* wk, const short8* wv,
                 f32x4 (&acc)[4][3]) {
    #pragma unroll
    for (int ks = 0; ks < 4; ++ks) {
      const int k0 = ks * 32 + quad * 8;
      #pragma unroll
      for (int rf = 0; rf < 4; ++rf) {
        const short8 af = *(const short8*)&Asm[rf * 16 + l15][k0];
        acc[rf][0] = MFMA(af, wq[ks], acc[rf][0], 0, 0, 0);
        acc[rf][1] = MFMA(af, wk[ks], acc[rf][1], 0, 0, 0);
        acc[rf][2] = MFMA(af, wv[ks], acc[rf][2], 0, 0, 0);
      }
    }
  };

  // MFMA attention for head h = g*4+wave. acc[wg] covers tokens 16wg..16wg+15
  // at (token=quad*4+r, dim=l15). Zero-padded K=32 (quads 2,3 supply zeros).
  auto ATTN = [&](int g, f32x4 (&acc)[4][3]) {
    const int h = g * 4 + wave;
    const int nq = g * 64 + wave * 16 + l15;
    const float bbq = qkv_b[nq];
    const float bbk = qkv_b[128 + nq];
    const float bbv = qkv_b[256 + nq];
    #pragma unroll
    for (int wg = 0; wg < 4; ++wg) {
      // stage Q,K transposed: s*[token][dim]
      #pragma unroll
      for (int r = 0; r < 4; ++r) {
        sq[quad * 4 + r][l15] = f2bf((acc[wg][0][r] + bbq) * 0.25f);
        sk[quad * 4 + r][l15] = f2bf(acc[wg][1][r] + bbk);
      }
      const unsigned pv0 = pk2(acc[wg][2][0] + bbv, acc[wg][2][1] + bbv);
      const unsigned pv1 = pk2(acc[wg][2][2] + bbv, acc[wg][2][3] + bbv);
      // QK^T: A=K[j][d], B=Q^T[d][i] -> S[j][i]; quads>=2 are K-pad (zero)
      short8 ka = {}, qb = {};
      if (quad < 2) {
        ka = *(const short8*)&sk[l15][quad * 8];
        qb = *(const short8*)&sq[l15][quad * 8];
      }
      const f32x4 s = MFMA(ka, qb, fz, 0, 0, 0);
      // lane (quad,l15) holds S[j=quad*4+r][i=l15]; valid iff quad==l15>>2
      const int i2 = l15 & 3;
      const int wl = wg * 4 + (l15 >> 2);
      const int n = n0 + wl;
      const int rem = n & 4095;
      const int wh = rem >> 6, wwi = rem & 63;
      const int yi = 2 * wh + (i2 >> 1);
      const int xi = 2 * wwi + (i2 & 1);
      const int regi = ((yi < 126) ? 0 : ((yi == 126) ? 1 : 2)) * 3
                     + ((xi < 126) ? 0 : ((xi == 126) ? 1 : 2));
      float p[4];
      #pragma unroll
      for (int j = 0; j < 4; ++j) {
        float d = s[j];
        const int idx = ((i2 >> 1) - (j >> 1) + 1) * 3 + ((i2 & 1) - (j & 1) + 1);
        d += rpb[idx * 8 + h];
        const int yj = 2 * wh + (j >> 1);
        const int xj = 2 * wwi + (j & 1);
        const int regj = ((yj < 126) ? 0 : ((yj == 126) ? 1 : 2)) * 3
                       + ((xj < 126) ? 0 : ((xj == 126) ? 1 : 2));
        if (regi != regj) d -= 100.f;
        p[j] = d;
      }
      const float mx = fmaxf(fmaxf(p[0], p[1]), fmaxf(p[2], p[3]));
      float es = 0.f;
      #pragma unroll
      for (int j = 0; j < 4; ++j) {
        p[j] = exp2f((p[j] - mx) * 1.44269504f);
        es += p[j];
      }
      const float inv = 1.f / es;
      const unsigned pd0 = pk2(p[0] * inv, p[1] * inv);
      const unsigned pd1 = pk2(p[2] * inv, p[3] * inv);
      // P -> PV A-frag: pull the 4 probs of row i=l15 from its valid lane
      const int srcp = (((l15 >> 2) << 4) | l15) << 2;
      const unsigned a0 = (unsigned)__builtin_amdgcn_ds_bpermute(srcp, (int)pd0);
      const unsigned a1 = (unsigned)__builtin_amdgcn_ds_bpermute(srcp, (int)pd1);
      const bool take = (quad == (l15 >> 3));
      const bool lo = ((l15 >> 2) & 1) == 0;
      V4 pa;
      pa.u[0] = (take && lo)  ? a0 : 0u;
      pa.u[1] = (take && lo)  ? a1 : 0u;
      pa.u[2] = (take && !lo) ? a0 : 0u;
      pa.u[3] = (take && !lo) ? a1 : 0u;
      // V -> PV B-frag: B[k=j][n=d] from acc via 4 bpermutes
      const int qs = (quad < 2) ? (quad * 2) : 0;
      const int sva = (qs * 16 + l15) << 2;
      const int svb = ((qs + 1) * 16 + l15) << 2;
      V4 vb;
      vb.u[0] = (unsigned)__builtin_amdgcn_ds_bpermute(sva, (int)pv0);
      vb.u[1] = (unsigned)__builtin_amdgcn_ds_bpermute(sva, (int)pv1);
      vb.u[2] = (unsigned)__builtin_amdgcn_ds_bpermute(svb, (int)pv0);
      vb.u[3] = (unsigned)__builtin_amdgcn_ds_bpermute(svb, (int)pv1);
      if (quad >= 2) { vb.u[0] = 0u; vb.u[1] = 0u; vb.u[2] = 0u; vb.u[3] = 0u; }
      const f32x4 o = MFMA(pa.s, vb.s, fz, 0, 0, 0);
      // O[i=quad*4+r][d=l15] -> ohs
      #pragma unroll
      for (int r = 0; r < 4; ++r)
        ohs[wg * 16 + quad * 4 + r][h * 16 + l15] = f2bf(o[r]);
    }
  };

  // ---- qkv g=0, prefetch g=1, attention g=0 ----
  f32x4 acc0[4][3] = {};
  QKV(w0q, w0k, w0v, acc0);
  short8 w1q[4], w1k[4], w1v[4];
  {
    const int nq = 64 + wave * 16 + l15;
    const unsigned short* bq = qkv_wt + (size_t)nq * 128;
    const unsigned short* bk = qkv_wt + (size_t)(128 + nq) * 128;
    const unsigned short* bv = qkv_wt + (size_t)(256 + nq) * 128;
    #pragma unroll
    for (int ks = 0; ks < 4; ++ks) {
      const int k0 = ks * 32 + quad * 8;
      w1q[ks] = *(const short8*)(bq + k0);
      w1k[ks] = *(const short8*)(bk + k0);
      w1v[ks] = *(const short8*)(bv + k0);
    }
  }
  ATTN(0, acc0);

  // ---- qkv g=1, prefetch proj weights, attention g=1 ----
  f32x4 acc1[4][3] = {};
  QKV(w1q, w1k, w1v, acc1);
  short8 pw[2][4];
  #pragma unroll
  for (int nt = 0; nt < 2; ++nt) {
    const unsigned short* br = proj_wt + (size_t)(wave * 32 + nt * 16 + l15) * 128;
    #pragma unroll
    for (int ks = 0; ks < 4; ++ks)
      pw[nt][ks] = *(const short8*)(br + ks * 32 + quad * 8);
  }
  ATTN(1, acc1);
  __syncthreads();  // S2: all ohs written

  // ---- proj GEMM K=128 + skip -> y stays in accp registers ----
  f32x4 accp[4][2] = {};
  #pragma unroll
  for (int ks = 0; ks < 4; ++ks) {
    const int k0 = ks * 32 + quad * 8;
    #pragma unroll
    for (int rf = 0; rf < 4; ++rf) {
      const short8 af = *(const short8*)&ohs[rf * 16 + l15][k0];
      accp[rf][0] = MFMA(af, pw[0][ks], accp[rf][0], 0, 0, 0);
      accp[rf][1] = MFMA(af, pw[1][ks], accp[rf][1], 0, 0, 0);
    }
  }
  const int ca = wave * 32 + l15;
  const int cb = wave * 32 + 16 + l15;
  {
    const float pba = proj_b[ca], pbb = proj_b[cb];
    #pragma unroll
    for (int rf = 0; rf < 4; ++rf) {
      #pragma unroll
      for (int r = 0; r < 4; ++r) {
        const int src = gsrc[rf * 16 + quad * 4 + r];
        const float* xr = x + (size_t)src * 128;
        accp[rf][0][r] += pba + xr[ca];
        accp[rf][1][r] += pbb + xr[cb];
      }
    }
  }

  // ---- LN2 stats: per-row partials via shfl, cross-wave via 2KB LDS ----
  #pragma unroll
  for (int rf = 0; rf < 4; ++rf) {
    #pragma unroll
    for (int r = 0; r < 4; ++r) {
      float sv = accp[rf][0][r] + accp[rf][1][r];
      float qv = accp[rf][0][r] * accp[rf][0][r] + accp[rf][1][r] * accp[rf][1][r];
      sv += __shfl_xor(sv, 1, 16); sv += __shfl_xor(sv, 2, 16);
      sv += __shfl_xor(sv, 4, 16); sv += __shfl_xor(sv, 8, 16);
      qv += __shfl_xor(qv, 1, 16); qv += __shfl_xor(qv, 2, 16);
      qv += __shfl_xor(qv, 4, 16); qv += __shfl_xor(qv, 8, 16);
      if (l15 == 0) {
        float2 pq; pq.x = sv; pq.y = qv;
        *(float2*)&part[(rf * 16 + quad * 4 + r) * 8 + wave * 2] = pq;
      }
    }
  }
  __syncthreads();  // S3

  {
    const float g2a = g2[ca], g2b = g2[cb];
    const float bta = bt2[ca], btb = bt2[cb];
    #pragma unroll
    for (int rf = 0; rf < 4; ++rf) {
      #pragma unroll
      for (int r = 0; r < 4; ++r) {
        const int row = rf * 16 + quad * 4 + r;
        const float2 p0 = *(const float2*)&part[row * 8 + 0];
        const float2 p1 = *(const float2*)&part[row * 8 + 2];
        const float2 p2 = *(const float2*)&part[row * 8 + 4];
        const float2 p3 = *(const float2*)&part[row * 8 + 6];
        const float mean = (p0.x + p1.x + p2.x + p3.x) * 0.0078125f;
        const float ex2 = (p0.y + p1.y + p2.y + p3.y) * 0.0078125f;
        const float rstd = rsqrtf(ex2 - mean * mean + 1e-5f);
        ys[row][ca] = f2bf((accp[rf][0][r] - mean) * rstd * g2a + bta);
        ys[row][cb] = f2bf((accp[rf][1][r] - mean) * rstd * g2b + btb);
      }
    }
  }
  __syncthreads();  // S4

  // ---- MLP: G1 swapped-form per 64-h chunk + GELU -> hid dbuf; G2 accum ----
  const unsigned short* w1t = wsw + 65536;   // [256][128]
  const unsigned short* w2t = wsw + 98304;   // [128][256]
  f32x4 am[4][2] = {};

  auto G1 = [&](int c, unsigned short (*hb)[72]) {
    f32x4 hacc[4] = {};
    const int ht = c * 4 + wave;
    const unsigned short* arow = w1t + (size_t)(ht * 16 + l15) * 128;
    #pragma unroll
    for (int ks = 0; ks < 4; ++ks) {
      const int k0 = ks * 32 + quad * 8;
      const short8 af = *(const short8*)(arow + k0);           // w1t as A-frag
      #pragma unroll
      for (int mt = 0; mt < 4; ++mt) {
        const short8 bf = *(const short8*)&ys[mt * 16 + l15][k0];  // ys as B-frag
        hacc[mt] = MFMA(af, bf, hacc[mt], 0, 0, 0);
      }
    }
    const int hbase = ht * 16 + quad * 4;
    const float4 bb = *(const float4*)(bias1 + hbase);
    #pragma unroll
    for (int mt = 0; mt < 4; ++mt) {
      ushort4v pk;
      #pragma unroll
      for (int r = 0; r < 4; ++r) {
        float v = hacc[mt][r] + ((const float*)&bb)[r];
        v = 0.5f * v * (1.f + erff(v * 0.70710678118654752f));
        pk[r] = f2bf(v);
      }
      *(ushort4v*)&hb[mt * 16 + l15][wave * 16 + quad * 4] = pk;
    }
  };
  auto G2 = [&](int c, const unsigned short (*hb)[72]) {
    #pragma unroll
    for (int ks = 0; ks < 2; ++ks) {
      const int k0 = ks * 32 + quad * 8;
      const int kg = c * 64 + k0;
      const short8 f0 = *(const short8*)(w2t + (size_t)ca * 256 + kg);
      const short8 f1 = *(const short8*)(w2t + (size_t)cb * 256 + kg);
      #pragma unroll
      for (int rf = 0; rf < 4; ++rf) {
        const short8 af = *(const short8*)&hb[rf * 16 + l15][k0];
        am[rf][0] = MFMA(af, f0, am[rf][0], 0, 0, 0);
        am[rf][1] = MFMA(af, f1, am[rf][1], 0, 0, 0);
      }
    }
  };

  G1(0, hid0);
  __syncthreads();  // S5
  G1(1, hid1); G2(0, hid0);
  __syncthreads();  // S6
  G1(2, hid0); G2(1, hid1);
  __syncthreads();  // S7
  G1(3, hid1); G2(2, hid0);
  __syncthreads();  // S8
  G2(3, hid1);

  // ---- final: out = y + bias2 + mlp (single global write) ----
  {
    const float b2a = bias2[ca], b2b = bias2[cb];
    #pragma unroll
    for (int rf = 0; rf < 4; ++rf) {
      #pragma unroll
      for (int r = 0; r < 4; ++r) {
        const int src = gsrc[rf * 16 + quad * 4 + r];
        float* orow = out + (size_t)src * 128;
        orow[ca] = accp[rf][0][r] + b2a + am[rf][0][r];
        orow[cb] = accp[rf][1][r] + b2b + am[rf][1][r];
      }
    }
  }
}

} // namespace

extern "C" void kernel_launch(void* const* d_in, const int* in_sizes, int n_in,
                              void* d_out, int out_size, void* d_ws, size_t ws_size,
                              hipStream_t stream) {
  const float* x      = (const float*)d_in[0];
  const float* qkv_w  = (const float*)d_in[1];
  const float* qkv_b  = (const float*)d_in[2];
  const float* proj_w = (const float*)d_in[3];
  const float* proj_b = (const float*)d_in[4];
  const float* rpb    = (const float*)d_in[5];
  const float* g1     = (const float*)d_in[6];
  const float* b1     = (const float*)d_in[7];
  const float* g2     = (const float*)d_in[8];
  const float* b2     = (const float*)d_in[9];
  const float* w1     = (const float*)d_in[10];
  const float* bias1  = (const float*)d_in[11];
  const float* w2     = (const float*)d_in[12];
  const float* bias2  = (const float*)d_in[13];
  float* out = (float*)d_out;
  unsigned short* wsw = (unsigned short*)d_ws;

  hipLaunchKernelGGL(prep_weights, dim3(512), dim3(256), 0, stream,
                     qkv_w, proj_w, w1, w2, wsw);
  hipLaunchKernelGGL(swin_fused, dim3(8192), dim3(256), 0, stream,
                     x, wsw, qkv_b, proj_b, rpb, g1, b1, g2, b2, bias1, bias2, out);
}

// Round 3
// 875.020 us; speedup vs baseline: 1.8952x; 1.0195x over previous
//
#include <hip/hip_runtime.h>
#include <math.h>

// Fused Swin block on MI355X: B=32, H=W=128, C=128, WS=2, SS=1, NH=8, HD=16
// One block = 16 windows (64 tokens). LN1 -> qkv GEMM (reg acc, per-head waves)
// -> MFMA attention (zero-padded K=32; softmax lane-local; P via 2 bpermutes,
// V via 4 bpermutes; tiny per-wave Q/K LDS transpose stage) -> proj GEMM K=128
// -> y kept in REGISTERS (LN2 stats via shfl + 2KB LDS partials; no y global
// roundtrip, out written exactly once) -> MLP chunked dbuf GEMMs.
// R3: NO cross-barrier register prefetch of weights (R2's 64 spilled regs ->
// 440MB scratch writebacks). Weights load inline at use (L2-hot, 256KB shared).
// x-skip dwords prefetched after S2 under the proj MFMAs. Target: no scratch,
// ~110 live regs < 128 cap at 4 blocks/CU (LDS 40,192B).
// MFMA layouts (m89/m91): A[m=lane&15][k=quad*8+j], B[k=quad*8+j][n=lane&15],
// D col=lane&15 row=quad*4+reg.

typedef __attribute__((ext_vector_type(8))) short short8;
typedef __attribute__((ext_vector_type(8))) unsigned short ushort8;
typedef __attribute__((ext_vector_type(4))) unsigned short ushort4v;
typedef __attribute__((ext_vector_type(4))) float f32x4;

#define MFMA __builtin_amdgcn_mfma_f32_16x16x32_bf16

__device__ inline unsigned short f2bf(float f) {
  union { float f; unsigned u; } v; v.f = f;
  unsigned r = (v.u + 0x7fffu + ((v.u >> 16) & 1u)) >> 16;
  return (unsigned short)r;
}
__device__ inline unsigned pk2(float a, float b) {
  return (unsigned)f2bf(a) | ((unsigned)f2bf(b) << 16);
}
union V4 { unsigned u[4]; short8 s; };

namespace {

// ws layout (bf16 elements): qkv_wt[384][128] @0, proj_wt[128][128] @49152,
// w1t[256][128] @65536, w2t[128][256] @98304. Total 131072 el = 256KB.
__global__ __launch_bounds__(256) void prep_weights(
    const float* __restrict__ qkv_w, const float* __restrict__ proj_w,
    const float* __restrict__ w1, const float* __restrict__ w2,
    unsigned short* __restrict__ ws)
{
  const int idx = blockIdx.x * 256 + threadIdx.x;  // grid covers 131072
  float v;
  if (idx < 49152) {            // qkv_wt[n][k] = qkv_w[k][n], n<384,k<128
    const int n = idx >> 7, k = idx & 127; v = qkv_w[k * 384 + n];
  } else if (idx < 65536) {     // proj_wt
    const int l = idx - 49152; const int n = l >> 7, k = l & 127;
    v = proj_w[k * 128 + n];
  } else if (idx < 98304) {     // w1t[n][k], n<256,k<128
    const int l = idx - 65536; const int n = l >> 7, k = l & 127;
    v = w1[k * 256 + n];
  } else {                      // w2t[n][k], n<128,k<256
    const int l = idx - 98304; const int n = l >> 8, k = l & 255;
    v = w2[k * 128 + n];
  }
  ws[idx] = f2bf(v);
}

__global__ __launch_bounds__(256, 4) void swin_fused(
    const float* __restrict__ x,
    const unsigned short* __restrict__ wsw,
    const float* __restrict__ qkv_b,
    const float* __restrict__ proj_b,
    const float* __restrict__ rpb,
    const float* __restrict__ g1,
    const float* __restrict__ b1,
    const float* __restrict__ g2,
    const float* __restrict__ bt2,
    const float* __restrict__ bias1,
    const float* __restrict__ bias2,
    float* __restrict__ out)
{
  // Regions: [0,256) gsrc | [256,17664) Asm(=ys) | [17664,22784) per-wave QK
  // stage (later: LN2 partials, hid0) | [22784,40192) ohs (later: hid1 tail)
  __shared__ __align__(16) unsigned char smem[40192];
  int* gsrc = (int*)smem;
  unsigned short (*Asm)[136] = (unsigned short(*)[136])(smem + 256);
  unsigned short (*ys)[136]  = (unsigned short(*)[136])(smem + 256);    // alias
  unsigned short (*ohs)[136] = (unsigned short(*)[136])(smem + 22784);
  unsigned short (*hid0)[72] = (unsigned short(*)[72])(smem + 17664);   // alias
  unsigned short (*hid1)[72] = (unsigned short(*)[72])(smem + 26880);   // alias
  float* part = (float*)(smem + 17664);                                 // [64][8]

  const int tid = threadIdx.x;
  const int n0 = blockIdx.x * 16;
  const int lane = tid & 63;
  const int wave = tid >> 6;
  const int l15 = lane & 15;
  const int quad = lane >> 4;
  const f32x4 fz = {0.f, 0.f, 0.f, 0.f};

  const unsigned short* qkv_wt = wsw;            // [384][128]
  const unsigned short* proj_wt = wsw + 49152;   // [128][128]

  // per-wave Q/K transpose stage: [16][20] bf16 each
  unsigned short (*sq)[20] = (unsigned short(*)[20])(smem + 17664 + wave * 1280);
  unsigned short (*sk)[20] = (unsigned short(*)[20])(smem + 17664 + wave * 1280 + 640);

  // ---- gather + LN1 -> bf16 Asm ----
  {
    const int r = tid >> 2;
    const int partc = tid & 3;
    const int n = n0 + (r >> 2);
    const int s = r & 3;
    const int b = n >> 12;
    const int rem = n & 4095;
    const int wh = rem >> 6, wwi = rem & 63;
    const int hp = (2 * wh + (s >> 1) + 1) & 127;
    const int wp = (2 * wwi + (s & 1) + 1) & 127;
    const int src = (b << 14) + (hp << 7) + wp;
    if (partc == 0) gsrc[r] = src;
    const float4* xr = (const float4*)(x + (size_t)src * 128 + partc * 32);
    float4 v[8];
    float sum = 0.f, ssq = 0.f;
    #pragma unroll
    for (int i = 0; i < 8; ++i) {
      v[i] = xr[i];
      sum += v[i].x + v[i].y + v[i].z + v[i].w;
      ssq += v[i].x * v[i].x + v[i].y * v[i].y + v[i].z * v[i].z + v[i].w * v[i].w;
    }
    sum += __shfl_xor(sum, 1, 4); sum += __shfl_xor(sum, 2, 4);
    ssq += __shfl_xor(ssq, 1, 4); ssq += __shfl_xor(ssq, 2, 4);
    const float mean = sum * 0.0078125f;
    const float var = ssq * 0.0078125f - mean * mean;
    const float rstd = rsqrtf(var + 1e-5f);
    const int c0 = partc * 32;
    #pragma unroll
    for (int i = 0; i < 8; ++i) {
      const int c = c0 + i * 4;
      const float4 gv = *(const float4*)(g1 + c);
      const float4 bv = *(const float4*)(b1 + c);
      ushort4v h4;
      h4.x = f2bf((v[i].x - mean) * rstd * gv.x + bv.x);
      h4.y = f2bf((v[i].y - mean) * rstd * gv.y + bv.y);
      h4.z = f2bf((v[i].z - mean) * rstd * gv.z + bv.z);
      h4.w = f2bf((v[i].w - mean) * rstd * gv.w + bv.w);
      *(ushort4v*)&Asm[r][c] = h4;
    }
  }
  __syncthreads();  // S1

  // qkv GEMM for head group g: weights loaded inline (L2-hot)
  auto QKV = [&](int g, f32x4 (&acc)[4][3]) {
    const int nq = g * 64 + wave * 16 + l15;
    const unsigned short* bq = qkv_wt + (size_t)nq * 128;
    const unsigned short* bk = qkv_wt + (size_t)(128 + nq) * 128;
    const unsigned short* bv = qkv_wt + (size_t)(256 + nq) * 128;
    #pragma unroll
    for (int ks = 0; ks < 4; ++ks) {
      const int k0 = ks * 32 + quad * 8;
      const short8 fq = *(const short8*)(bq + k0);
      const short8 fk = *(const short8*)(bk + k0);
      const short8 fv = *(const short8*)(bv + k0);
      #pragma unroll
      for (int rf = 0; rf < 4; ++rf) {
        const short8 af = *(const short8*)&Asm[rf * 16 + l15][k0];
        acc[rf][0] = MFMA(af, fq, acc[rf][0], 0, 0, 0);
        acc[rf][1] = MFMA(af, fk, acc[rf][1], 0, 0, 0);
        acc[rf][2] = MFMA(af, fv, acc[rf][2], 0, 0, 0);
      }
    }
  };

  // MFMA attention for head h = g*4+wave. acc[wg] covers tokens 16wg..16wg+15
  // at (token=quad*4+r, dim=l15). Zero-padded K=32 (quads 2,3 supply zeros).
  auto ATTN = [&](int g, f32x4 (&acc)[4][3]) {
    const int h = g * 4 + wave;
    const int nq = g * 64 + wave * 16 + l15;
    const float bbq = qkv_b[nq];
    const float bbk = qkv_b[128 + nq];
    const float bbv = qkv_b[256 + nq];
    #pragma unroll
    for (int wg = 0; wg < 4; ++wg) {
      // stage Q,K transposed: s*[token][dim]
      #pragma unroll
      for (int r = 0; r < 4; ++r) {
        sq[quad * 4 + r][l15] = f2bf((acc[wg][0][r] + bbq) * 0.25f);
        sk[quad * 4 + r][l15] = f2bf(acc[wg][1][r] + bbk);
      }
      const unsigned pv0 = pk2(acc[wg][2][0] + bbv, acc[wg][2][1] + bbv);
      const unsigned pv1 = pk2(acc[wg][2][2] + bbv, acc[wg][2][3] + bbv);
      // QK^T: A=K[j][d], B=Q^T[d][i] -> S[j][i]; quads>=2 are K-pad (zero)
      short8 ka = {}, qb = {};
      if (quad < 2) {
        ka = *(const short8*)&sk[l15][quad * 8];
        qb = *(const short8*)&sq[l15][quad * 8];
      }
      const f32x4 s = MFMA(ka, qb, fz, 0, 0, 0);
      // lane (quad,l15) holds S[j=quad*4+r][i=l15]; valid iff quad==l15>>2
      const int i2 = l15 & 3;
      const int wl = wg * 4 + (l15 >> 2);
      const int n = n0 + wl;
      const int rem = n & 4095;
      const int wh = rem >> 6, wwi = rem & 63;
      const int yi = 2 * wh + (i2 >> 1);
      const int xi = 2 * wwi + (i2 & 1);
      const int regi = ((yi < 126) ? 0 : ((yi == 126) ? 1 : 2)) * 3
                     + ((xi < 126) ? 0 : ((xi == 126) ? 1 : 2));
      float p[4];
      #pragma unroll
      for (int j = 0; j < 4; ++j) {
        float d = s[j];
        const int idx = ((i2 >> 1) - (j >> 1) + 1) * 3 + ((i2 & 1) - (j & 1) + 1);
        d += rpb[idx * 8 + h];
        const int yj = 2 * wh + (j >> 1);
        const int xj = 2 * wwi + (j & 1);
        const int regj = ((yj < 126) ? 0 : ((yj == 126) ? 1 : 2)) * 3
                       + ((xj < 126) ? 0 : ((xj == 126) ? 1 : 2));
        if (regi != regj) d -= 100.f;
        p[j] = d;
      }
      const float mx = fmaxf(fmaxf(p[0], p[1]), fmaxf(p[2], p[3]));
      float es = 0.f;
      #pragma unroll
      for (int j = 0; j < 4; ++j) {
        p[j] = exp2f((p[j] - mx) * 1.44269504f);
        es += p[j];
      }
      const float inv = 1.f / es;
      const unsigned pd0 = pk2(p[0] * inv, p[1] * inv);
      const unsigned pd1 = pk2(p[2] * inv, p[3] * inv);
      // P -> PV A-frag: pull the 4 probs of row i=l15 from its valid lane
      const int srcp = (((l15 >> 2) << 4) | l15) << 2;
      const unsigned a0 = (unsigned)__builtin_amdgcn_ds_bpermute(srcp, (int)pd0);
      const unsigned a1 = (unsigned)__builtin_amdgcn_ds_bpermute(srcp, (int)pd1);
      const bool take = (quad == (l15 >> 3));
      const bool lo = ((l15 >> 2) & 1) == 0;
      V4 pa;
      pa.u[0] = (take && lo)  ? a0 : 0u;
      pa.u[1] = (take && lo)  ? a1 : 0u;
      pa.u[2] = (take && !lo) ? a0 : 0u;
      pa.u[3] = (take && !lo) ? a1 : 0u;
      // V -> PV B-frag: B[k=j][n=d] from acc via 4 bpermutes
      const int qs = (quad < 2) ? (quad * 2) : 0;
      const int sva = (qs * 16 + l15) << 2;
      const int svb = ((qs + 1) * 16 + l15) << 2;
      V4 vb;
      vb.u[0] = (unsigned)__builtin_amdgcn_ds_bpermute(sva, (int)pv0);
      vb.u[1] = (unsigned)__builtin_amdgcn_ds_bpermute(sva, (int)pv1);
      vb.u[2] = (unsigned)__builtin_amdgcn_ds_bpermute(svb, (int)pv0);
      vb.u[3] = (unsigned)__builtin_amdgcn_ds_bpermute(svb, (int)pv1);
      if (quad >= 2) { vb.u[0] = 0u; vb.u[1] = 0u; vb.u[2] = 0u; vb.u[3] = 0u; }
      const f32x4 o = MFMA(pa.s, vb.s, fz, 0, 0, 0);
      // O[i=quad*4+r][d=l15] -> ohs
      #pragma unroll
      for (int r = 0; r < 4; ++r)
        ohs[wg * 16 + quad * 4 + r][h * 16 + l15] = f2bf(o[r]);
    }
  };

  // ---- head group 0, then head group 1 (no cross-barrier reg prefetch) ----
  {
    f32x4 acc0[4][3] = {};
    QKV(0, acc0);
    ATTN(0, acc0);
  }
  {
    f32x4 acc1[4][3] = {};
    QKV(1, acc1);
    ATTN(1, acc1);
  }
  __syncthreads();  // S2: all ohs written

  const int ca = wave * 32 + l15;
  const int cb = wave * 32 + 16 + l15;

  // ---- prefetch x-skip dwords (latency hides under proj MFMAs) ----
  float xa[4][4], xb[4][4];
  #pragma unroll
  for (int rf = 0; rf < 4; ++rf) {
    #pragma unroll
    for (int r = 0; r < 4; ++r) {
      const float* xr = x + (size_t)gsrc[rf * 16 + quad * 4 + r] * 128;
      xa[rf][r] = xr[ca];
      xb[rf][r] = xr[cb];
    }
  }

  // ---- proj GEMM K=128 + skip -> y stays in accp registers ----
  f32x4 accp[4][2] = {};
  {
    const unsigned short* br0 = proj_wt + (size_t)ca * 128;
    const unsigned short* br1 = proj_wt + (size_t)cb * 128;
    #pragma unroll
    for (int ks = 0; ks < 4; ++ks) {
      const int k0 = ks * 32 + quad * 8;
      const short8 f0 = *(const short8*)(br0 + k0);
      const short8 f1 = *(const short8*)(br1 + k0);
      #pragma unroll
      for (int rf = 0; rf < 4; ++rf) {
        const short8 af = *(const short8*)&ohs[rf * 16 + l15][k0];
        accp[rf][0] = MFMA(af, f0, accp[rf][0], 0, 0, 0);
        accp[rf][1] = MFMA(af, f1, accp[rf][1], 0, 0, 0);
      }
    }
  }
  {
    const float pba = proj_b[ca], pbb = proj_b[cb];
    #pragma unroll
    for (int rf = 0; rf < 4; ++rf) {
      #pragma unroll
      for (int r = 0; r < 4; ++r) {
        accp[rf][0][r] += pba + xa[rf][r];
        accp[rf][1][r] += pbb + xb[rf][r];
      }
    }
  }

  // ---- LN2 stats: per-row partials via shfl, cross-wave via 2KB LDS ----
  #pragma unroll
  for (int rf = 0; rf < 4; ++rf) {
    #pragma unroll
    for (int r = 0; r < 4; ++r) {
      float sv = accp[rf][0][r] + accp[rf][1][r];
      float qv = accp[rf][0][r] * accp[rf][0][r] + accp[rf][1][r] * accp[rf][1][r];
      sv += __shfl_xor(sv, 1, 16); sv += __shfl_xor(sv, 2, 16);
      sv += __shfl_xor(sv, 4, 16); sv += __shfl_xor(sv, 8, 16);
      qv += __shfl_xor(qv, 1, 16); qv += __shfl_xor(qv, 2, 16);
      qv += __shfl_xor(qv, 4, 16); qv += __shfl_xor(qv, 8, 16);
      if (l15 == 0) {
        float2 pq; pq.x = sv; pq.y = qv;
        *(float2*)&part[(rf * 16 + quad * 4 + r) * 8 + wave * 2] = pq;
      }
    }
  }
  __syncthreads();  // S3

  {
    const float g2a = g2[ca], g2b = g2[cb];
    const float bta = bt2[ca], btb = bt2[cb];
    #pragma unroll
    for (int rf = 0; rf < 4; ++rf) {
      #pragma unroll
      for (int r = 0; r < 4; ++r) {
        const int row = rf * 16 + quad * 4 + r;
        const float2 p0 = *(const float2*)&part[row * 8 + 0];
        const float2 p1 = *(const float2*)&part[row * 8 + 2];
        const float2 p2 = *(const float2*)&part[row * 8 + 4];
        const float2 p3 = *(const float2*)&part[row * 8 + 6];
        const float mean = (p0.x + p1.x + p2.x + p3.x) * 0.0078125f;
        const float ex2 = (p0.y + p1.y + p2.y + p3.y) * 0.0078125f;
        const float rstd = rsqrtf(ex2 - mean * mean + 1e-5f);
        ys[row][ca] = f2bf((accp[rf][0][r] - mean) * rstd * g2a + bta);
        ys[row][cb] = f2bf((accp[rf][1][r] - mean) * rstd * g2b + btb);
      }
    }
  }
  __syncthreads();  // S4

  // ---- MLP: G1 swapped-form per 64-h chunk + GELU -> hid dbuf; G2 accum ----
  const unsigned short* w1t = wsw + 65536;   // [256][128]
  const unsigned short* w2t = wsw + 98304;   // [128][256]
  f32x4 am[4][2] = {};

  auto G1 = [&](int c, unsigned short (*hb)[72]) {
    f32x4 hacc[4] = {};
    const int ht = c * 4 + wave;
    const unsigned short* arow = w1t + (size_t)(ht * 16 + l15) * 128;
    #pragma unroll
    for (int ks = 0; ks < 4; ++ks) {
      const int k0 = ks * 32 + quad * 8;
      const short8 af = *(const short8*)(arow + k0);           // w1t as A-frag
      #pragma unroll
      for (int mt = 0; mt < 4; ++mt) {
        const short8 bf = *(const short8*)&ys[mt * 16 + l15][k0];  // ys as B-frag
        hacc[mt] = MFMA(af, bf, hacc[mt], 0, 0, 0);
      }
    }
    const int hbase = ht * 16 + quad * 4;
    const float4 bb = *(const float4*)(bias1 + hbase);
    #pragma unroll
    for (int mt = 0; mt < 4; ++mt) {
      ushort4v pk;
      #pragma unroll
      for (int r = 0; r < 4; ++r) {
        float v = hacc[mt][r] + ((const float*)&bb)[r];
        v = 0.5f * v * (1.f + erff(v * 0.70710678118654752f));
        pk[r] = f2bf(v);
      }
      *(ushort4v*)&hb[mt * 16 + l15][wave * 16 + quad * 4] = pk;
    }
  };
  auto G2 = [&](int c, const unsigned short (*hb)[72]) {
    #pragma unroll
    for (int ks = 0; ks < 2; ++ks) {
      const int k0 = ks * 32 + quad * 8;
      const int kg = c * 64 + k0;
      const short8 f0 = *(const short8*)(w2t + (size_t)ca * 256 + kg);
      const short8 f1 = *(const short8*)(w2t + (size_t)cb * 256 + kg);
      #pragma unroll
      for (int rf = 0; rf < 4; ++rf) {
        const short8 af = *(const short8*)&hb[rf * 16 + l15][k0];
        am[rf][0] = MFMA(af, f0, am[rf][0], 0, 0, 0);
        am[rf][1] = MFMA(af, f1, am[rf][1], 0, 0, 0);
      }
    }
  };

  G1(0, hid0);
  __syncthreads();  // S5
  G1(1, hid1); G2(0, hid0);
  __syncthreads();  // S6
  G1(2, hid0); G2(1, hid1);
  __syncthreads();  // S7
  G1(3, hid1); G2(2, hid0);
  __syncthreads();  // S8
  G2(3, hid1);

  // ---- final: out = y + bias2 + mlp (single global write) ----
  {
    const float b2a = bias2[ca], b2b = bias2[cb];
    #pragma unroll
    for (int rf = 0; rf < 4; ++rf) {
      #pragma unroll
      for (int r = 0; r < 4; ++r) {
        const int src = gsrc[rf * 16 + quad * 4 + r];
        float* orow = out + (size_t)src * 128;
        orow[ca] = accp[rf][0][r] + b2a + am[rf][0][r];
        orow[cb] = accp[rf][1][r] + b2b + am[rf][1][r];
      }
    }
  }
}

} // namespace

extern "C" void kernel_launch(void* const* d_in, const int* in_sizes, int n_in,
                              void* d_out, int out_size, void* d_ws, size_t ws_size,
                              hipStream_t stream) {
  const float* x      = (const float*)d_in[0];
  const float* qkv_w  = (const float*)d_in[1];
  const float* qkv_b  = (const float*)d_in[2];
  const float* proj_w = (const float*)d_in[3];
  const float* proj_b = (const float*)d_in[4];
  const float* rpb    = (const float*)d_in[5];
  const float* g1     = (const float*)d_in[6];
  const float* b1     = (const float*)d_in[7];
  const float* g2     = (const float*)d_in[8];
  const float* b2     = (const float*)d_in[9];
  const float* w1     = (const float*)d_in[10];
  const float* bias1  = (const float*)d_in[11];
  const float* w2     = (const float*)d_in[12];
  const float* bias2  = (const float*)d_in[13];
  float* out = (float*)d_out;
  unsigned short* wsw = (unsigned short*)d_ws;

  hipLaunchKernelGGL(prep_weights, dim3(512), dim3(256), 0, stream,
                     qkv_w, proj_w, w1, w2, wsw);
  hipLaunchKernelGGL(swin_fused, dim3(8192), dim3(256), 0, stream,
                     x, wsw, qkv_b, proj_b, rpb, g1, b1, g2, b2, bias1, bias2, out);
}